// Round 16
// baseline (25941.956 us; speedup 1.0000x reference)
//
#include <hip/hip_runtime.h>
#include <hip/hip_bf16.h>

#define NN 6144
#define DD 64
#define NL 3
#define KK 24
#define BT2 128  // pair-tile dimension (xmat kernel)
#define KH2 16   // k-quarter staged at a time
#define MB 4     // rows per block (mlp kernel)
#define KCLAMP 7.99881172180175781f
#define BANDLO 7.0f   // x<=7.0 => r(x) < RB provably (validated rounds 13-15)

typedef unsigned long long ull;

// Bit-level emulation of XLA CPU f32 tanh, FMA variant. Verified bit-exact
// vs reference (rounds 2-15, absmax 0.0).
__device__ __forceinline__ float tanh_xla(float x) {
  float xc = fminf(fmaxf(x, -KCLAMP), KCLAMP);
  float x2 = xc * xc;
  float p = -2.76076847742355e-16f;
  p = fmaf(p, x2, 2.00018790482477e-13f);
  p = fmaf(p, x2, -8.60467152213735e-11f);
  p = fmaf(p, x2, 5.12229709037114e-08f);
  p = fmaf(p, x2, 1.48572235717979e-05f);
  p = fmaf(p, x2, 6.37261928875436e-04f);
  p = fmaf(p, x2, 4.89352455891786e-03f);
  p = xc * p;
  float q = 1.19825839466702e-06f;
  q = fmaf(q, x2, 1.18534705686654e-04f);
  q = fmaf(q, x2, 2.26843463243900e-03f);
  q = fmaf(q, x2, 4.89352518554385e-03f);
  float r = p / q;
  return (fabsf(x) < 0.0004f) ? x : r;
}

__device__ __forceinline__ ull shfl_xor_u64(ull v, int m) {
  unsigned lo = __shfl_xor((unsigned)v, m);
  unsigned hi = __shfl_xor((unsigned)(v >> 32), m);
  return ((ull)hi << 32) | lo;
}

// Kernel A: 3-layer tanh MLP chains (bit-matches Eigen). Also zeroes the
// per-row super counters and the fallback counter (graph-replay safe).
__global__ __launch_bounds__(256) void mlp_kernel(
    const int* __restrict__ idx, const float* __restrict__ scale_set,
    const float* __restrict__ emb1, const float* __restrict__ emb2,
    const float* __restrict__ W1, const float* __restrict__ b1,
    const float* __restrict__ W2, const float* __restrict__ b2,
    float* __restrict__ vt1, float* __restrict__ vt2,
    unsigned* __restrict__ supercnt, unsigned* __restrict__ fbcnt) {
  __shared__ float Wt1[DD][DD];
  __shared__ float Wt2[DD][DD];
  __shared__ float bsh1[DD], bsh2[DD];
  __shared__ __align__(16) float o1sh[MB][DD];
  __shared__ __align__(16) float o2sh[MB][DD];
  const int t = threadIdx.x;
  const int r = t >> 6;
  const int j = t & 63;
  const int grow = blockIdx.x * MB + r;

  if (t < 12) supercnt[blockIdx.x * 12 + t] = 0u;   // 1536*12 = NL*NN
  if (blockIdx.x == 0 && t == 0) fbcnt[0] = 0u;

  {
    int g = idx[grow];
    if (j < 16) {
      ((float4*)&o1sh[r][0])[j] = ((const float4*)(emb1 + (size_t)g * DD))[j];
      ((float4*)&o2sh[r][0])[j] = ((const float4*)(emb2 + (size_t)g * DD))[j];
    }
  }

  for (int l = 0; l < NL; ++l) {
    __syncthreads();
    {
      const float* w1p = W1 + ((size_t)l * DD + j) * DD + r * 16;
      const float* w2p = W2 + ((size_t)l * DD + j) * DD + r * 16;
#pragma unroll
      for (int w = 0; w < 4; ++w) {
        float4 a = *(const float4*)(w1p + 4 * w);
        float4 b = *(const float4*)(w2p + 4 * w);
        int k0 = r * 16 + 4 * w;
        Wt1[k0 + 0][j] = a.x; Wt1[k0 + 1][j] = a.y;
        Wt1[k0 + 2][j] = a.z; Wt1[k0 + 3][j] = a.w;
        Wt2[k0 + 0][j] = b.x; Wt2[k0 + 1][j] = b.y;
        Wt2[k0 + 2][j] = b.z; Wt2[k0 + 3][j] = b.w;
      }
    }
    if (t < DD) { bsh1[t] = b1[l * DD + t]; bsh2[t] = b2[l * DD + t]; }
    __syncthreads();

    const float s = scale_set[l];
    float a1 = 0.0f, a2 = 0.0f;
#pragma unroll
    for (int kb = 0; kb < 16; ++kb) {
      float4 s1 = ((const float4*)&o1sh[r][0])[kb];
      float4 s2 = ((const float4*)&o2sh[r][0])[kb];
      int k0 = 4 * kb;
      a1 = fmaf(s1.x * s, Wt1[k0 + 0][j], a1);
      a1 = fmaf(s1.y * s, Wt1[k0 + 1][j], a1);
      a1 = fmaf(s1.z * s, Wt1[k0 + 2][j], a1);
      a1 = fmaf(s1.w * s, Wt1[k0 + 3][j], a1);
      a2 = fmaf(s2.x * s, Wt2[k0 + 0][j], a2);
      a2 = fmaf(s2.y * s, Wt2[k0 + 1][j], a2);
      a2 = fmaf(s2.z * s, Wt2[k0 + 2][j], a2);
      a2 = fmaf(s2.w * s, Wt2[k0 + 3][j], a2);
    }
    float t1 = tanh_xla(3.0f * (a1 + bsh1[j]));
    float t2 = tanh_xla(3.0f * (a2 + bsh2[j]));
    __syncthreads();
    o1sh[r][j] = t1;
    o2sh[r][j] = t2;
    vt1[((size_t)l * DD + j) * NN + grow] = t1;
    vt2[((size_t)l * DD + j) * NN + grow] = t2;
  }
}

// Pass 1: antisymmetric pair-tile GEMM (validated chains; bit-exact mirror).
// Classifies every element in-register and writes ONLY classification bytes
// (1B per 8 cols) to global pb + super records. No x store, no LDS overlay.
__global__ __launch_bounds__(256) void xmat_kernel(
    const float* __restrict__ vt1, const float* __restrict__ vt2,
    unsigned char* __restrict__ pbB,
    unsigned* __restrict__ supercnt, uint2* __restrict__ superrec) {
  __shared__ float R1h[KH2][BT2];
  __shared__ float R2h[KH2][BT2];
  __shared__ float C1h[KH2][BT2];
  __shared__ float C2h[KH2][BT2];

  const int a = blockIdx.x;
  const int b = blockIdx.y;
  if (b < a) return;
  const int l = blockIdx.z;
  const int t = threadIdx.x;
  const int r0 = a * BT2;
  const int c0 = b * BT2;
  const float* w1 = vt1 + (size_t)l * DD * NN;
  const float* w2 = vt2 + (size_t)l * DD * NN;
  const unsigned RB = __float_as_uint(tanh_xla(8.0f));  // plateau value bits

  const int ty = t >> 4;
  const int tx = t & 15;
  const int sk = t >> 4;
  const int sq = (t & 15) * 8;

  float acc1[8][8] = {{0.f}}, acc2[8][8] = {{0.f}};

#pragma unroll
  for (int h = 0; h < 4; ++h) {
    __syncthreads();
    {
      const size_t src = (size_t)(h * KH2 + sk) * NN;
      *(float4*)&R1h[sk][sq]     = *(const float4*)(w1 + src + r0 + sq);
      *(float4*)&R1h[sk][sq + 4] = *(const float4*)(w1 + src + r0 + sq + 4);
      *(float4*)&R2h[sk][sq]     = *(const float4*)(w2 + src + r0 + sq);
      *(float4*)&R2h[sk][sq + 4] = *(const float4*)(w2 + src + r0 + sq + 4);
      *(float4*)&C1h[sk][sq]     = *(const float4*)(w1 + src + c0 + sq);
      *(float4*)&C1h[sk][sq + 4] = *(const float4*)(w1 + src + c0 + sq + 4);
      *(float4*)&C2h[sk][sq]     = *(const float4*)(w2 + src + c0 + sq);
      *(float4*)&C2h[sk][sq + 4] = *(const float4*)(w2 + src + c0 + sq + 4);
    }
    __syncthreads();
#pragma unroll 2
    for (int kk = 0; kk < KH2; ++kk) {
      float r1[8], r2[8], c1[8], c2[8];
      *(float4*)&r1[0] = *(const float4*)&R1h[kk][8 * ty];
      *(float4*)&r1[4] = *(const float4*)&R1h[kk][8 * ty + 4];
      *(float4*)&r2[0] = *(const float4*)&R2h[kk][8 * ty];
      *(float4*)&r2[4] = *(const float4*)&R2h[kk][8 * ty + 4];
      *(float4*)&c1[0] = *(const float4*)&C1h[kk][8 * tx];
      *(float4*)&c1[4] = *(const float4*)&C1h[kk][8 * tx + 4];
      *(float4*)&c2[0] = *(const float4*)&C2h[kk][8 * tx];
      *(float4*)&c2[4] = *(const float4*)&C2h[kk][8 * tx + 4];
#pragma unroll
      for (int i = 0; i < 8; ++i)
#pragma unroll
        for (int j = 0; j < 8; ++j) {
          acc1[i][j] = fmaf(r1[i], c2[j], acc1[i][j]);  // v1_r . v2_c
          acc2[i][j] = fmaf(r2[i], c1[j], acc2[i][j]);  // v2_r . v1_c
        }
    }
  }

  // Direct tile: classify (plateau || band==RB -> bit; band>RB -> super).
#pragma unroll
  for (int i = 0; i < 8; ++i) {
    unsigned bits = 0;
#pragma unroll
    for (int j = 0; j < 8; ++j) {
      float x = 3.0f * (acc1[i][j] - acc2[i][j]);
      bool rb = (x >= KCLAMP);
      if (!rb && x > BANDLO) {
        unsigned vb = __float_as_uint(tanh_xla(x));
        if (vb == RB) rb = true;
        else if (vb > RB) {
          size_t grow = (size_t)l * NN + (r0 + 8 * ty + i);
          unsigned slot = atomicAdd(&supercnt[grow], 1u);
          if (slot < 8u)
            superrec[grow * 8 + slot] = make_uint2(vb, (unsigned)(c0 + 8 * tx + j));
        }
      }
      if (rb) bits |= 1u << j;
    }
    pbB[((size_t)l * NN + (r0 + 8 * ty + i)) * 768 + b * 16 + tx] = (unsigned char)bits;
  }
  // Mirror tile (b>a): mirror x = 3*(acc2-acc1) bitwise; same classification.
  if (b > a) {
#pragma unroll
    for (int j = 0; j < 8; ++j) {
      unsigned bits = 0;
#pragma unroll
      for (int i = 0; i < 8; ++i) {
        float x = 3.0f * (acc2[i][j] - acc1[i][j]);
        bool rb = (x >= KCLAMP);
        if (!rb && x > BANDLO) {
          unsigned vb = __float_as_uint(tanh_xla(x));
          if (vb == RB) rb = true;
          else if (vb > RB) {
            size_t grow = (size_t)l * NN + (c0 + 8 * tx + j);
            unsigned slot = atomicAdd(&supercnt[grow], 1u);
            if (slot < 8u)
              superrec[grow * 8 + slot] = make_uint2(vb, (unsigned)(r0 + 8 * ty + i));
          }
        }
        if (rb) bits |= 1u << i;
      }
      pbB[((size_t)l * NN + (c0 + 8 * tx + j)) * 768 + a * 16 + ty] = (unsigned char)bits;
    }
  }
}

// Pass 2 (fast): one wave per row, selection purely from bitmaps.
// Winners = S supers (value desc, idx asc) + first (24-S) RB bits by index.
// Rows needing the exact slow path (S>8 or RB-deficient) are appended to a
// fallback list and left untouched (fback_kernel finishes them).
__global__ __launch_bounds__(256, 4) void topk_kernel(
    const ulonglong2* __restrict__ pb, const unsigned* __restrict__ supercnt,
    const uint2* __restrict__ superrec, unsigned* __restrict__ fbcnt,
    unsigned* __restrict__ fblist, float* __restrict__ out) {
  const int t = threadIdx.x;
  const int w = t >> 6;
  const int lane = t & 63;
  const int row = blockIdx.x * 4 + w;     // layer*NN + row
  float* rp = out + (size_t)row * NN;
  const float Rclamp = tanh_xla(8.0f);
  const ull KOFF = 1ull << 62;

  ull bmx = 0ull, bmy = 0ull;
  if (lane < 48) {
    ulonglong2 bmv = pb[(size_t)row * 48 + lane];
    bmx = bmv.x; bmy = bmv.y;
  }
  const unsigned S = supercnt[row];       // wave-uniform
  bool fb = (S > 8u);
  const unsigned E = (S < 24u) ? S : 24u;
  const unsigned C24 = 24u - E;

  ull skey = 0ull;
  if (!fb && lane < (int)S) {
    uint2 rec = superrec[(size_t)row * 8 + lane];
    skey = KOFF | ((ull)rec.x << 32) | (ull)(0xFFFFu - rec.y);
  }

  // Rank RB bits: exclusive prefix of per-tile popcounts across lanes.
  unsigned cnt = (unsigned)__popcll(bmx) + (unsigned)__popcll(bmy);
  unsigned p = cnt;
#pragma unroll
  for (int d = 1; d < 64; d <<= 1) {
    unsigned o2 = __shfl_up(p, d);
    if (lane >= d) p += o2;
  }
  unsigned excl = p - cnt;
  unsigned total = __shfl(p, 63);
  if (total < C24) fb = true;             // wave-uniform

  if (fb) {
    if (lane == 0) {
      unsigned pos = atomicAdd(fbcnt, 1u);
      fblist[pos] = (unsigned)row;
    }
    return;                               // fback_kernel owns this row
  }

  // Extract supers: e-th winner parked in lane e (keys unique).
  float wv = 0.0f;
  int wi = 0;
  for (unsigned e = 0; e < E; ++e) {
    ull win = skey;
#pragma unroll
    for (int d = 1; d < 64; d <<= 1) {
      ull o2 = shfl_xor_u64(win, d);
      win = (o2 > win) ? o2 : win;
    }
    if (lane == (int)e) {
      wv = __uint_as_float((unsigned)((win >> 32) & 0x3FFFFFFFu));
      wi = 0xFFFF - (int)(win & 0xFFFFull);
    }
    if (skey == win) skey = 0ull;
  }
  // Zero the row, drain all wave stores, then scatter.
  float4 z = make_float4(0.f, 0.f, 0.f, 0.f);
  for (int sb = 0; sb < 24; ++sb)
    *(float4*)(rp + (size_t)(sb * 64 + lane) * 4) = z;
  asm volatile("s_waitcnt vmcnt(0)" ::: "memory");
  int need = (int)C24 - (int)excl;
  if (need > (int)cnt) need = (int)cnt;
  if (need > 0 && lane < 48) {
    int base = lane * 128;
    int done = 0;
    ull m = bmx;
    while (done < need && m) {
      int k = __builtin_ctzll(m);
      rp[base + k] = Rclamp;
      m &= m - 1; ++done;
    }
    m = bmy;
    while (done < need && m) {
      int k = __builtin_ctzll(m);
      rp[base + 64 + k] = Rclamp;
      m &= m - 1; ++done;
    }
  }
  if (lane < (int)E && wv > 0.0f) rp[wi] = wv;
}

// Fallback kernel: 1 wave per listed row (usually zero rows -> instant exit).
// Recomputes x with the identical ascending-k fmaf chains (bit-exact: IEEE
// mul commutes per term, same chain order as xmat/reference), then runs the
// verbatim round-9 full-list machinery + zero+scatter.
__global__ __launch_bounds__(64) void fback_kernel(
    const float* __restrict__ vt1, const float* __restrict__ vt2,
    const unsigned* __restrict__ fbcnt, const unsigned* __restrict__ fblist,
    float* __restrict__ out) {
  const int lane = threadIdx.x;
  const unsigned RB = __float_as_uint(tanh_xla(8.0f));
  const ull KOFF = 1ull << 62;
  const ull RKEYHI = (ull)RB << 32;
  const double EMPTYD = __longlong_as_double((long long)KOFF);
  const unsigned n = fbcnt[0];

  for (unsigned it = blockIdx.x; it < n; it += gridDim.x) {
    const int row = (int)fblist[it];
    const int l = row / NN;
    const int r = row - l * NN;
    float* rp = out + (size_t)row * NN;
    const float* w1 = vt1 + (size_t)l * DD * NN;
    const float* w2 = vt2 + (size_t)l * DD * NN;

    float r1v[DD], r2v[DD];
#pragma unroll
    for (int k = 0; k < DD; ++k) {
      r1v[k] = w1[(size_t)k * NN + r];
      r2v[k] = w2[(size_t)k * NN + r];
    }

    ull mlo = 0ull, mhi = 0ull;
    double s[KK];
#pragma unroll
    for (int q = 0; q < KK; ++q) s[q] = EMPTYD;
    ull s0k = KOFF;

    for (int sb = 0; sb < 24; ++sb) {
      const unsigned gbase = (unsigned)(sb * 256 + lane * 4);
      float xv[4];
#pragma unroll
      for (int jj = 0; jj < 4; ++jj) {
        const int col = (int)gbase + jj;
        float a1 = 0.0f, a2 = 0.0f;
        const float* p2 = w2 + col;
        const float* p1 = w1 + col;
#pragma unroll
        for (int k = 0; k < DD; ++k) {
          a1 = fmaf(r1v[k], p2[(size_t)k * NN], a1);
          a2 = fmaf(r2v[k], p1[(size_t)k * NN], a2);
        }
        xv[jj] = 3.0f * (a1 - a2);
      }
      unsigned nib = 0u;
#pragma unroll
      for (int jj = 0; jj < 4; ++jj) {
        float x = xv[jj];
        if (x >= KCLAMP) {
          nib |= 1u << jj;
        } else if (x > 0.0f) {
          float tv = tanh_xla(x);
          ull key = KOFF | ((ull)__float_as_uint(tv) << 32) |
                    (ull)(0xFFFFu - (gbase + jj));
          if (key > s0k) {
            double kd = __longlong_as_double((long long)key);
#pragma unroll
            for (int i = 0; i < KK - 1; ++i)
              s[i] = fmin(s[i + 1], fmax(s[i], kd));
            s[KK - 1] = fmax(s[KK - 1], kd);
            s0k = (ull)__double_as_longlong(s[0]);
          }
        }
      }
      if (sb < 16) mlo |= ((ull)nib) << (sb * 4);
      else         mhi |= ((ull)nib) << ((sb - 16) * 4);
    }

    float wv = 0.0f;
    int wi = 0;
    for (int rr = 0; rr < KK; ++rr) {
      ull pk = KOFF;
      if (mlo | mhi) {
        int e = mlo ? __builtin_ctzll(mlo) : (64 + __builtin_ctzll(mhi));
        int pidx = ((e >> 2) << 8) + lane * 4 + (e & 3);
        pk = KOFF | RKEYHI | (ull)(0xFFFFu - (unsigned)pidx);
      }
      ull lk = (ull)__double_as_longlong(s[KK - 1]);
      bool fromList = lk > pk;
      ull cand = fromList ? lk : pk;
      ull win = cand;
#pragma unroll
      for (int d = 1; d < 64; d <<= 1) {
        ull o2 = shfl_xor_u64(win, d);
        win = (o2 > win) ? o2 : win;
      }
      if (win == KOFF) break;
      if (lane == rr) {
        wv = __uint_as_float((unsigned)((win >> 32) & 0x3FFFFFFFu));
        wi = 0xFFFF - (int)(win & 0xFFFFull);
      }
      if (cand == win) {
        if (fromList) {
#pragma unroll
          for (int i = KK - 1; i > 0; --i) s[i] = s[i - 1];
          s[0] = EMPTYD;
        } else {
          if (mlo) mlo &= mlo - 1;
          else     mhi &= mhi - 1;
        }
      }
    }

    float4 z = make_float4(0.f, 0.f, 0.f, 0.f);
    for (int sb = 0; sb < 24; ++sb)
      *(float4*)(rp + (size_t)(sb * 64 + lane) * 4) = z;
    asm volatile("s_waitcnt vmcnt(0)" ::: "memory");
    if (wv > 0.0f) rp[wi] = wv;
  }
}

extern "C" void kernel_launch(void* const* d_in, const int* in_sizes, int n_in,
                              void* d_out, int out_size, void* d_ws, size_t ws_size,
                              hipStream_t stream) {
  const int*   idx       = (const int*)d_in[0];
  const float* scale_set = (const float*)d_in[2];
  const float* emb1      = (const float*)d_in[3];
  const float* emb2      = (const float*)d_in[4];
  const float* W1        = (const float*)d_in[5];
  const float* b1        = (const float*)d_in[6];
  const float* W2        = (const float*)d_in[7];
  const float* b2        = (const float*)d_in[8];
  float* out = (float*)d_out;

  const size_t VS = (size_t)NL * NN * DD;
  float* vt1 = (float*)d_ws;                              // 4.7 MB
  float* vt2 = vt1 + VS;                                  // 4.7 MB
  unsigned char* pbB = (unsigned char*)(vt2 + VS);        // [NL*NN][48][16B] = 14.2 MB
  unsigned* supercnt = (unsigned*)(pbB + (size_t)NL * NN * 768);   // 74 KB
  uint2* superrec = (uint2*)(supercnt + (size_t)NL * NN);          // 1.2 MB
  unsigned* fbcnt = (unsigned*)(superrec + (size_t)NL * NN * 8);   // 4 B (+pad)
  unsigned* fblist = fbcnt + 16;                                   // 74 KB

  mlp_kernel<<<NN / MB, 256, 0, stream>>>(idx, scale_set, emb1, emb2, W1, b1, W2, b2,
                                          vt1, vt2, supercnt, fbcnt);
  xmat_kernel<<<dim3(NN / BT2, NN / BT2, NL), 256, 0, stream>>>(
      vt1, vt2, pbB, supercnt, superrec);
  topk_kernel<<<(NL * NN) / 4, 256, 0, stream>>>(
      (const ulonglong2*)pbB, supercnt, superrec, fbcnt, fblist, out);
  fback_kernel<<<256, 64, 0, stream>>>(vt1, vt2, fbcnt, fblist, out);
}

// Round 17
// 25930.560 us; speedup vs baseline: 1.0004x; 1.0004x over previous
//
#include <hip/hip_runtime.h>
#include <hip/hip_bf16.h>

#define NN 6144
#define DD 64
#define NL 3
#define KK 24
#define BT2 128  // pair-tile dimension (xmat kernel)
#define KH2 16   // k-quarter staged at a time
#define MB 4     // rows per block (mlp kernel)
#define SRCAP 64 // super records per row (one per extraction lane)
#define KCLAMP 7.99881172180175781f
#define BANDLO 7.0f   // x<=7.0 => r(x) < RB provably (validated rounds 13-16)

typedef unsigned long long ull;

// Bit-level emulation of XLA CPU f32 tanh, FMA variant. Verified bit-exact
// vs reference (rounds 2-16, absmax 0.0).
__device__ __forceinline__ float tanh_xla(float x) {
  float xc = fminf(fmaxf(x, -KCLAMP), KCLAMP);
  float x2 = xc * xc;
  float p = -2.76076847742355e-16f;
  p = fmaf(p, x2, 2.00018790482477e-13f);
  p = fmaf(p, x2, -8.60467152213735e-11f);
  p = fmaf(p, x2, 5.12229709037114e-08f);
  p = fmaf(p, x2, 1.48572235717979e-05f);
  p = fmaf(p, x2, 6.37261928875436e-04f);
  p = fmaf(p, x2, 4.89352455891786e-03f);
  p = xc * p;
  float q = 1.19825839466702e-06f;
  q = fmaf(q, x2, 1.18534705686654e-04f);
  q = fmaf(q, x2, 2.26843463243900e-03f);
  q = fmaf(q, x2, 4.89352518554385e-03f);
  float r = p / q;
  return (fabsf(x) < 0.0004f) ? x : r;
}

__device__ __forceinline__ ull shfl_xor_u64(ull v, int m) {
  unsigned lo = __shfl_xor((unsigned)v, m);
  unsigned hi = __shfl_xor((unsigned)(v >> 32), m);
  return ((ull)hi << 32) | lo;
}

// Kernel A: 3-layer tanh MLP chains (bit-matches Eigen). Also zeroes the
// per-row super counters and the fallback counter (graph-replay safe).
__global__ __launch_bounds__(256) void mlp_kernel(
    const int* __restrict__ idx, const float* __restrict__ scale_set,
    const float* __restrict__ emb1, const float* __restrict__ emb2,
    const float* __restrict__ W1, const float* __restrict__ b1,
    const float* __restrict__ W2, const float* __restrict__ b2,
    float* __restrict__ vt1, float* __restrict__ vt2,
    unsigned* __restrict__ supercnt, unsigned* __restrict__ fbcnt) {
  __shared__ float Wt1[DD][DD];
  __shared__ float Wt2[DD][DD];
  __shared__ float bsh1[DD], bsh2[DD];
  __shared__ __align__(16) float o1sh[MB][DD];
  __shared__ __align__(16) float o2sh[MB][DD];
  const int t = threadIdx.x;
  const int r = t >> 6;
  const int j = t & 63;
  const int grow = blockIdx.x * MB + r;

  if (t < 12) supercnt[blockIdx.x * 12 + t] = 0u;   // 1536*12 = NL*NN
  if (blockIdx.x == 0 && t == 0) fbcnt[0] = 0u;

  {
    int g = idx[grow];
    if (j < 16) {
      ((float4*)&o1sh[r][0])[j] = ((const float4*)(emb1 + (size_t)g * DD))[j];
      ((float4*)&o2sh[r][0])[j] = ((const float4*)(emb2 + (size_t)g * DD))[j];
    }
  }

  for (int l = 0; l < NL; ++l) {
    __syncthreads();
    {
      const float* w1p = W1 + ((size_t)l * DD + j) * DD + r * 16;
      const float* w2p = W2 + ((size_t)l * DD + j) * DD + r * 16;
#pragma unroll
      for (int w = 0; w < 4; ++w) {
        float4 a = *(const float4*)(w1p + 4 * w);
        float4 b = *(const float4*)(w2p + 4 * w);
        int k0 = r * 16 + 4 * w;
        Wt1[k0 + 0][j] = a.x; Wt1[k0 + 1][j] = a.y;
        Wt1[k0 + 2][j] = a.z; Wt1[k0 + 3][j] = a.w;
        Wt2[k0 + 0][j] = b.x; Wt2[k0 + 1][j] = b.y;
        Wt2[k0 + 2][j] = b.z; Wt2[k0 + 3][j] = b.w;
      }
    }
    if (t < DD) { bsh1[t] = b1[l * DD + t]; bsh2[t] = b2[l * DD + t]; }
    __syncthreads();

    const float s = scale_set[l];
    float a1 = 0.0f, a2 = 0.0f;
#pragma unroll
    for (int kb = 0; kb < 16; ++kb) {
      float4 s1 = ((const float4*)&o1sh[r][0])[kb];
      float4 s2 = ((const float4*)&o2sh[r][0])[kb];
      int k0 = 4 * kb;
      a1 = fmaf(s1.x * s, Wt1[k0 + 0][j], a1);
      a1 = fmaf(s1.y * s, Wt1[k0 + 1][j], a1);
      a1 = fmaf(s1.z * s, Wt1[k0 + 2][j], a1);
      a1 = fmaf(s1.w * s, Wt1[k0 + 3][j], a1);
      a2 = fmaf(s2.x * s, Wt2[k0 + 0][j], a2);
      a2 = fmaf(s2.y * s, Wt2[k0 + 1][j], a2);
      a2 = fmaf(s2.z * s, Wt2[k0 + 2][j], a2);
      a2 = fmaf(s2.w * s, Wt2[k0 + 3][j], a2);
    }
    float t1 = tanh_xla(3.0f * (a1 + bsh1[j]));
    float t2 = tanh_xla(3.0f * (a2 + bsh2[j]));
    __syncthreads();
    o1sh[r][j] = t1;
    o2sh[r][j] = t2;
    vt1[((size_t)l * DD + j) * NN + grow] = t1;
    vt2[((size_t)l * DD + j) * NN + grow] = t2;
  }
}

// Pass 1: antisymmetric pair-tile GEMM (validated chains; bit-exact mirror).
// Classifies every element in-register and writes ONLY classification bytes
// (1B per 8 cols) to global pb + super records (cap 64/row).
__global__ __launch_bounds__(256) void xmat_kernel(
    const float* __restrict__ vt1, const float* __restrict__ vt2,
    unsigned char* __restrict__ pbB,
    unsigned* __restrict__ supercnt, uint2* __restrict__ superrec) {
  __shared__ float R1h[KH2][BT2];
  __shared__ float R2h[KH2][BT2];
  __shared__ float C1h[KH2][BT2];
  __shared__ float C2h[KH2][BT2];

  const int a = blockIdx.x;
  const int b = blockIdx.y;
  if (b < a) return;
  const int l = blockIdx.z;
  const int t = threadIdx.x;
  const int r0 = a * BT2;
  const int c0 = b * BT2;
  const float* w1 = vt1 + (size_t)l * DD * NN;
  const float* w2 = vt2 + (size_t)l * DD * NN;
  const unsigned RB = __float_as_uint(tanh_xla(8.0f));  // plateau value bits

  const int ty = t >> 4;
  const int tx = t & 15;
  const int sk = t >> 4;
  const int sq = (t & 15) * 8;

  float acc1[8][8] = {{0.f}}, acc2[8][8] = {{0.f}};

#pragma unroll
  for (int h = 0; h < 4; ++h) {
    __syncthreads();
    {
      const size_t src = (size_t)(h * KH2 + sk) * NN;
      *(float4*)&R1h[sk][sq]     = *(const float4*)(w1 + src + r0 + sq);
      *(float4*)&R1h[sk][sq + 4] = *(const float4*)(w1 + src + r0 + sq + 4);
      *(float4*)&R2h[sk][sq]     = *(const float4*)(w2 + src + r0 + sq);
      *(float4*)&R2h[sk][sq + 4] = *(const float4*)(w2 + src + r0 + sq + 4);
      *(float4*)&C1h[sk][sq]     = *(const float4*)(w1 + src + c0 + sq);
      *(float4*)&C1h[sk][sq + 4] = *(const float4*)(w1 + src + c0 + sq + 4);
      *(float4*)&C2h[sk][sq]     = *(const float4*)(w2 + src + c0 + sq);
      *(float4*)&C2h[sk][sq + 4] = *(const float4*)(w2 + src + c0 + sq + 4);
    }
    __syncthreads();
#pragma unroll 2
    for (int kk = 0; kk < KH2; ++kk) {
      float r1[8], r2[8], c1[8], c2[8];
      *(float4*)&r1[0] = *(const float4*)&R1h[kk][8 * ty];
      *(float4*)&r1[4] = *(const float4*)&R1h[kk][8 * ty + 4];
      *(float4*)&r2[0] = *(const float4*)&R2h[kk][8 * ty];
      *(float4*)&r2[4] = *(const float4*)&R2h[kk][8 * ty + 4];
      *(float4*)&c1[0] = *(const float4*)&C1h[kk][8 * tx];
      *(float4*)&c1[4] = *(const float4*)&C1h[kk][8 * tx + 4];
      *(float4*)&c2[0] = *(const float4*)&C2h[kk][8 * tx];
      *(float4*)&c2[4] = *(const float4*)&C2h[kk][8 * tx + 4];
#pragma unroll
      for (int i = 0; i < 8; ++i)
#pragma unroll
        for (int j = 0; j < 8; ++j) {
          acc1[i][j] = fmaf(r1[i], c2[j], acc1[i][j]);  // v1_r . v2_c
          acc2[i][j] = fmaf(r2[i], c1[j], acc2[i][j]);  // v2_r . v1_c
        }
    }
  }

  // Direct tile: classify (plateau || band==RB -> bit; band>RB -> super).
#pragma unroll
  for (int i = 0; i < 8; ++i) {
    unsigned bits = 0;
#pragma unroll
    for (int j = 0; j < 8; ++j) {
      float x = 3.0f * (acc1[i][j] - acc2[i][j]);
      bool rb = (x >= KCLAMP);
      if (!rb && x > BANDLO) {
        unsigned vb = __float_as_uint(tanh_xla(x));
        if (vb == RB) rb = true;
        else if (vb > RB) {
          size_t grow = (size_t)l * NN + (r0 + 8 * ty + i);
          unsigned slot = atomicAdd(&supercnt[grow], 1u);
          if (slot < (unsigned)SRCAP)
            superrec[grow * SRCAP + slot] = make_uint2(vb, (unsigned)(c0 + 8 * tx + j));
        }
      }
      if (rb) bits |= 1u << j;
    }
    pbB[((size_t)l * NN + (r0 + 8 * ty + i)) * 768 + b * 16 + tx] = (unsigned char)bits;
  }
  // Mirror tile (b>a): mirror x = 3*(acc2-acc1) bitwise; same classification.
  if (b > a) {
#pragma unroll
    for (int j = 0; j < 8; ++j) {
      unsigned bits = 0;
#pragma unroll
      for (int i = 0; i < 8; ++i) {
        float x = 3.0f * (acc2[i][j] - acc1[i][j]);
        bool rb = (x >= KCLAMP);
        if (!rb && x > BANDLO) {
          unsigned vb = __float_as_uint(tanh_xla(x));
          if (vb == RB) rb = true;
          else if (vb > RB) {
            size_t grow = (size_t)l * NN + (c0 + 8 * tx + j);
            unsigned slot = atomicAdd(&supercnt[grow], 1u);
            if (slot < (unsigned)SRCAP)
              superrec[grow * SRCAP + slot] = make_uint2(vb, (unsigned)(r0 + 8 * ty + i));
          }
        }
        if (rb) bits |= 1u << i;
      }
      pbB[((size_t)l * NN + (c0 + 8 * tx + j)) * 768 + a * 16 + ty] = (unsigned char)bits;
    }
  }
}

// Pass 2 (fast): one wave per row, selection purely from bitmaps + records.
// Winners = top min(S,24) supers (value desc, idx asc; supers beat every RB
// entry since their value > RB) + first (24 - that) RB bits by index.
// Fallback only if S > 64 (record overflow) or RB-deficient (both ~never).
__global__ __launch_bounds__(256, 4) void topk_kernel(
    const ulonglong2* __restrict__ pb, const unsigned* __restrict__ supercnt,
    const uint2* __restrict__ superrec, unsigned* __restrict__ fbcnt,
    unsigned* __restrict__ fblist, float* __restrict__ out) {
  const int t = threadIdx.x;
  const int w = t >> 6;
  const int lane = t & 63;
  const int row = blockIdx.x * 4 + w;     // layer*NN + row
  float* rp = out + (size_t)row * NN;
  const float Rclamp = tanh_xla(8.0f);
  const ull KOFF = 1ull << 62;

  ull bmx = 0ull, bmy = 0ull;
  if (lane < 48) {
    ulonglong2 bmv = pb[(size_t)row * 48 + lane];
    bmx = bmv.x; bmy = bmv.y;
  }
  const unsigned S = supercnt[row];       // wave-uniform
  bool fb = (S > (unsigned)SRCAP);
  const unsigned E = (S < 24u) ? S : 24u;
  const unsigned C24 = 24u - E;

  ull skey = 0ull;
  if (!fb && lane < (int)S) {
    uint2 rec = superrec[(size_t)row * SRCAP + lane];
    skey = KOFF | ((ull)rec.x << 32) | (ull)(0xFFFFu - rec.y);
  }

  // Rank RB bits: exclusive prefix of per-tile popcounts across lanes.
  unsigned cnt = (unsigned)__popcll(bmx) + (unsigned)__popcll(bmy);
  unsigned p = cnt;
#pragma unroll
  for (int d = 1; d < 64; d <<= 1) {
    unsigned o2 = __shfl_up(p, d);
    if (lane >= d) p += o2;
  }
  unsigned excl = p - cnt;
  unsigned total = __shfl(p, 63);
  if (total < C24) fb = true;             // wave-uniform

  if (fb) {
    if (lane == 0) {
      unsigned pos = atomicAdd(fbcnt, 1u);
      fblist[pos] = (unsigned)row;
    }
    return;                               // fback_kernel owns this row
  }

  // Extract supers: e-th winner parked in lane e (keys unique).
  float wv = 0.0f;
  int wi = 0;
  for (unsigned e = 0; e < E; ++e) {
    ull win = skey;
#pragma unroll
    for (int d = 1; d < 64; d <<= 1) {
      ull o2 = shfl_xor_u64(win, d);
      win = (o2 > win) ? o2 : win;
    }
    if (lane == (int)e) {
      wv = __uint_as_float((unsigned)((win >> 32) & 0x3FFFFFFFu));
      wi = 0xFFFF - (int)(win & 0xFFFFull);
    }
    if (skey == win) skey = 0ull;
  }
  // Zero the row, drain all wave stores, then scatter.
  float4 z = make_float4(0.f, 0.f, 0.f, 0.f);
  for (int sb = 0; sb < 24; ++sb)
    *(float4*)(rp + (size_t)(sb * 64 + lane) * 4) = z;
  asm volatile("s_waitcnt vmcnt(0)" ::: "memory");
  int need = (int)C24 - (int)excl;
  if (need > (int)cnt) need = (int)cnt;
  if (need > 0 && lane < 48) {
    int base = lane * 128;
    int done = 0;
    ull m = bmx;
    while (done < need && m) {
      int k = __builtin_ctzll(m);
      rp[base + k] = Rclamp;
      m &= m - 1; ++done;
    }
    m = bmy;
    while (done < need && m) {
      int k = __builtin_ctzll(m);
      rp[base + 64 + k] = Rclamp;
      m &= m - 1; ++done;
    }
  }
  if (lane < (int)E && wv > 0.0f) rp[wi] = wv;
}

// Fallback kernel: 1 wave per listed row (normally zero rows -> instant
// exit). Recomputes x with the identical ascending-k fmaf chains via float4
// column loads (bit-exact: per-column chain order unchanged), then runs the
// verbatim round-9 full-list machinery + zero+scatter.
__global__ __launch_bounds__(64) void fback_kernel(
    const float* __restrict__ vt1, const float* __restrict__ vt2,
    const unsigned* __restrict__ fbcnt, const unsigned* __restrict__ fblist,
    float* __restrict__ out) {
  const int lane = threadIdx.x;
  const unsigned RB = __float_as_uint(tanh_xla(8.0f));
  const ull KOFF = 1ull << 62;
  const ull RKEYHI = (ull)RB << 32;
  const double EMPTYD = __longlong_as_double((long long)KOFF);
  const unsigned n = fbcnt[0];

  for (unsigned it = blockIdx.x; it < n; it += gridDim.x) {
    const int row = (int)fblist[it];
    const int l = row / NN;
    const int r = row - l * NN;
    float* rp = out + (size_t)row * NN;
    const float* w1 = vt1 + (size_t)l * DD * NN;
    const float* w2 = vt2 + (size_t)l * DD * NN;

    float r1v[DD], r2v[DD];
#pragma unroll
    for (int k = 0; k < DD; ++k) {
      r1v[k] = w1[(size_t)k * NN + r];
      r2v[k] = w2[(size_t)k * NN + r];
    }

    ull mlo = 0ull, mhi = 0ull;
    double s[KK];
#pragma unroll
    for (int q = 0; q < KK; ++q) s[q] = EMPTYD;
    ull s0k = KOFF;

    for (int sb = 0; sb < 24; ++sb) {
      const unsigned gbase = (unsigned)(sb * 256 + lane * 4);
      // Vectorized recompute: 4 columns per lane, ascending-k fmaf chains
      // (identical per-column order -> bit-exact).
      float a1v[4] = {0.f, 0.f, 0.f, 0.f}, a2v[4] = {0.f, 0.f, 0.f, 0.f};
#pragma unroll
      for (int k = 0; k < DD; ++k) {
        float4 c1 = *(const float4*)(w1 + (size_t)k * NN + gbase);
        float4 c2 = *(const float4*)(w2 + (size_t)k * NN + gbase);
        a1v[0] = fmaf(r1v[k], c2.x, a1v[0]);
        a1v[1] = fmaf(r1v[k], c2.y, a1v[1]);
        a1v[2] = fmaf(r1v[k], c2.z, a1v[2]);
        a1v[3] = fmaf(r1v[k], c2.w, a1v[3]);
        a2v[0] = fmaf(r2v[k], c1.x, a2v[0]);
        a2v[1] = fmaf(r2v[k], c1.y, a2v[1]);
        a2v[2] = fmaf(r2v[k], c1.z, a2v[2]);
        a2v[3] = fmaf(r2v[k], c1.w, a2v[3]);
      }
      unsigned nib = 0u;
#pragma unroll
      for (int jj = 0; jj < 4; ++jj) {
        float x = 3.0f * (a1v[jj] - a2v[jj]);
        if (x >= KCLAMP) {
          nib |= 1u << jj;
        } else if (x > 0.0f) {
          float tv = tanh_xla(x);
          ull key = KOFF | ((ull)__float_as_uint(tv) << 32) |
                    (ull)(0xFFFFu - (gbase + jj));
          if (key > s0k) {
            double kd = __longlong_as_double((long long)key);
#pragma unroll
            for (int i = 0; i < KK - 1; ++i)
              s[i] = fmin(s[i + 1], fmax(s[i], kd));
            s[KK - 1] = fmax(s[KK - 1], kd);
            s0k = (ull)__double_as_longlong(s[0]);
          }
        }
      }
      if (sb < 16) mlo |= ((ull)nib) << (sb * 4);
      else         mhi |= ((ull)nib) << ((sb - 16) * 4);
    }

    float wv = 0.0f;
    int wi = 0;
    for (int rr = 0; rr < KK; ++rr) {
      ull pk = KOFF;
      if (mlo | mhi) {
        int e = mlo ? __builtin_ctzll(mlo) : (64 + __builtin_ctzll(mhi));
        int pidx = ((e >> 2) << 8) + lane * 4 + (e & 3);
        pk = KOFF | RKEYHI | (ull)(0xFFFFu - (unsigned)pidx);
      }
      ull lk = (ull)__double_as_longlong(s[KK - 1]);
      bool fromList = lk > pk;
      ull cand = fromList ? lk : pk;
      ull win = cand;
#pragma unroll
      for (int d = 1; d < 64; d <<= 1) {
        ull o2 = shfl_xor_u64(win, d);
        win = (o2 > win) ? o2 : win;
      }
      if (win == KOFF) break;
      if (lane == rr) {
        wv = __uint_as_float((unsigned)((win >> 32) & 0x3FFFFFFFu));
        wi = 0xFFFF - (int)(win & 0xFFFFull);
      }
      if (cand == win) {
        if (fromList) {
#pragma unroll
          for (int i = KK - 1; i > 0; --i) s[i] = s[i - 1];
          s[0] = EMPTYD;
        } else {
          if (mlo) mlo &= mlo - 1;
          else     mhi &= mhi - 1;
        }
      }
    }

    float4 z = make_float4(0.f, 0.f, 0.f, 0.f);
    for (int sb = 0; sb < 24; ++sb)
      *(float4*)(rp + (size_t)(sb * 64 + lane) * 4) = z;
    asm volatile("s_waitcnt vmcnt(0)" ::: "memory");
    if (wv > 0.0f) rp[wi] = wv;
  }
}

extern "C" void kernel_launch(void* const* d_in, const int* in_sizes, int n_in,
                              void* d_out, int out_size, void* d_ws, size_t ws_size,
                              hipStream_t stream) {
  const int*   idx       = (const int*)d_in[0];
  const float* scale_set = (const float*)d_in[2];
  const float* emb1      = (const float*)d_in[3];
  const float* emb2      = (const float*)d_in[4];
  const float* W1        = (const float*)d_in[5];
  const float* b1        = (const float*)d_in[6];
  const float* W2        = (const float*)d_in[7];
  const float* b2        = (const float*)d_in[8];
  float* out = (float*)d_out;

  const size_t VS = (size_t)NL * NN * DD;
  float* vt1 = (float*)d_ws;                              // 4.7 MB
  float* vt2 = vt1 + VS;                                  // 4.7 MB
  unsigned char* pbB = (unsigned char*)(vt2 + VS);        // [NL*NN][48][16B] = 14.2 MB
  unsigned* supercnt = (unsigned*)(pbB + (size_t)NL * NN * 768);      // 74 KB
  uint2* superrec = (uint2*)(supercnt + (size_t)NL * NN);             // 9.4 MB
  unsigned* fbcnt = (unsigned*)(superrec + (size_t)NL * NN * SRCAP); // 4 B (+pad)
  unsigned* fblist = fbcnt + 16;                                      // 74 KB

  mlp_kernel<<<NN / MB, 256, 0, stream>>>(idx, scale_set, emb1, emb2, W1, b1, W2, b2,
                                          vt1, vt2, supercnt, fbcnt);
  xmat_kernel<<<dim3(NN / BT2, NN / BT2, NL), 256, 0, stream>>>(
      vt1, vt2, pbB, supercnt, superrec);
  topk_kernel<<<(NL * NN) / 4, 256, 0, stream>>>(
      (const ulonglong2*)pbB, supercnt, superrec, fbcnt, fblist, out);
  fback_kernel<<<256, 64, 0, stream>>>(vt1, vt2, fbcnt, fblist, out);
}

// Round 18
// 25903.772 us; speedup vs baseline: 1.0015x; 1.0010x over previous
//
#include <hip/hip_runtime.h>
#include <hip/hip_bf16.h>

#define NN 6144
#define DD 64
#define NL 3
#define KK 24
#define BT2 128  // pair-tile dimension (xmat kernel)
#define KH2 16   // k-quarter staged at a time
#define MB 4     // rows per block (mlp kernel)
#define SRCAP 512 // super records per row (measured S ~ 90 +- 10)
#define RECOFF 1024  // float offset of record area inside each out row
#define KCLAMP 7.99881172180175781f
#define BANDLO 6.0f  // x<=6.0 => r(x) <= tanh(6)+1e-6 = 1-1.1e-5 < RB-9e-6 (10x margin)

typedef unsigned long long ull;

// Bit-level emulation of XLA CPU f32 tanh, FMA variant. Verified bit-exact
// vs reference (rounds 2-17, absmax 0.0).
__device__ __forceinline__ float tanh_xla(float x) {
  float xc = fminf(fmaxf(x, -KCLAMP), KCLAMP);
  float x2 = xc * xc;
  float p = -2.76076847742355e-16f;
  p = fmaf(p, x2, 2.00018790482477e-13f);
  p = fmaf(p, x2, -8.60467152213735e-11f);
  p = fmaf(p, x2, 5.12229709037114e-08f);
  p = fmaf(p, x2, 1.48572235717979e-05f);
  p = fmaf(p, x2, 6.37261928875436e-04f);
  p = fmaf(p, x2, 4.89352455891786e-03f);
  p = xc * p;
  float q = 1.19825839466702e-06f;
  q = fmaf(q, x2, 1.18534705686654e-04f);
  q = fmaf(q, x2, 2.26843463243900e-03f);
  q = fmaf(q, x2, 4.89352518554385e-03f);
  float r = p / q;
  return (fabsf(x) < 0.0004f) ? x : r;
}

__device__ __forceinline__ ull shfl_xor_u64(ull v, int m) {
  unsigned lo = __shfl_xor((unsigned)v, m);
  unsigned hi = __shfl_xor((unsigned)(v >> 32), m);
  return ((ull)hi << 32) | lo;
}

// Kernel A: 3-layer tanh MLP chains (bit-matches Eigen). Also zeroes the
// per-row super counters and the fallback counter (graph-replay safe).
__global__ __launch_bounds__(256) void mlp_kernel(
    const int* __restrict__ idx, const float* __restrict__ scale_set,
    const float* __restrict__ emb1, const float* __restrict__ emb2,
    const float* __restrict__ W1, const float* __restrict__ b1,
    const float* __restrict__ W2, const float* __restrict__ b2,
    float* __restrict__ vt1, float* __restrict__ vt2,
    unsigned* __restrict__ supercnt, unsigned* __restrict__ fbcnt) {
  __shared__ float Wt1[DD][DD];
  __shared__ float Wt2[DD][DD];
  __shared__ float bsh1[DD], bsh2[DD];
  __shared__ __align__(16) float o1sh[MB][DD];
  __shared__ __align__(16) float o2sh[MB][DD];
  const int t = threadIdx.x;
  const int r = t >> 6;
  const int j = t & 63;
  const int grow = blockIdx.x * MB + r;

  if (t < 12) supercnt[blockIdx.x * 12 + t] = 0u;   // 1536*12 = NL*NN
  if (blockIdx.x == 0 && t == 0) fbcnt[0] = 0u;

  {
    int g = idx[grow];
    if (j < 16) {
      ((float4*)&o1sh[r][0])[j] = ((const float4*)(emb1 + (size_t)g * DD))[j];
      ((float4*)&o2sh[r][0])[j] = ((const float4*)(emb2 + (size_t)g * DD))[j];
    }
  }

  for (int l = 0; l < NL; ++l) {
    __syncthreads();
    {
      const float* w1p = W1 + ((size_t)l * DD + j) * DD + r * 16;
      const float* w2p = W2 + ((size_t)l * DD + j) * DD + r * 16;
#pragma unroll
      for (int w = 0; w < 4; ++w) {
        float4 a = *(const float4*)(w1p + 4 * w);
        float4 b = *(const float4*)(w2p + 4 * w);
        int k0 = r * 16 + 4 * w;
        Wt1[k0 + 0][j] = a.x; Wt1[k0 + 1][j] = a.y;
        Wt1[k0 + 2][j] = a.z; Wt1[k0 + 3][j] = a.w;
        Wt2[k0 + 0][j] = b.x; Wt2[k0 + 1][j] = b.y;
        Wt2[k0 + 2][j] = b.z; Wt2[k0 + 3][j] = b.w;
      }
    }
    if (t < DD) { bsh1[t] = b1[l * DD + t]; bsh2[t] = b2[l * DD + t]; }
    __syncthreads();

    const float s = scale_set[l];
    float a1 = 0.0f, a2 = 0.0f;
#pragma unroll
    for (int kb = 0; kb < 16; ++kb) {
      float4 s1 = ((const float4*)&o1sh[r][0])[kb];
      float4 s2 = ((const float4*)&o2sh[r][0])[kb];
      int k0 = 4 * kb;
      a1 = fmaf(s1.x * s, Wt1[k0 + 0][j], a1);
      a1 = fmaf(s1.y * s, Wt1[k0 + 1][j], a1);
      a1 = fmaf(s1.z * s, Wt1[k0 + 2][j], a1);
      a1 = fmaf(s1.w * s, Wt1[k0 + 3][j], a1);
      a2 = fmaf(s2.x * s, Wt2[k0 + 0][j], a2);
      a2 = fmaf(s2.y * s, Wt2[k0 + 1][j], a2);
      a2 = fmaf(s2.z * s, Wt2[k0 + 2][j], a2);
      a2 = fmaf(s2.w * s, Wt2[k0 + 3][j], a2);
    }
    float t1 = tanh_xla(3.0f * (a1 + bsh1[j]));
    float t2 = tanh_xla(3.0f * (a2 + bsh2[j]));
    __syncthreads();
    o1sh[r][j] = t1;
    o2sh[r][j] = t2;
    vt1[((size_t)l * DD + j) * NN + grow] = t1;
    vt2[((size_t)l * DD + j) * NN + grow] = t2;
  }
}

// Pass 1: antisymmetric pair-tile GEMM (validated chains; bit-exact mirror).
// Classifies every element in-register: plateau/band==RB -> bitmap bit;
// band>RB -> super record appended into the OUTPUT ROW's scratch area
// (out[row*NN + RECOFF ..], 512 uint2 = 4KB; topk reads then zeroes it).
__global__ __launch_bounds__(256) void xmat_kernel(
    const float* __restrict__ vt1, const float* __restrict__ vt2,
    unsigned char* __restrict__ pbB,
    unsigned* __restrict__ supercnt, float* __restrict__ out) {
  __shared__ float R1h[KH2][BT2];
  __shared__ float R2h[KH2][BT2];
  __shared__ float C1h[KH2][BT2];
  __shared__ float C2h[KH2][BT2];

  const int a = blockIdx.x;
  const int b = blockIdx.y;
  if (b < a) return;
  const int l = blockIdx.z;
  const int t = threadIdx.x;
  const int r0 = a * BT2;
  const int c0 = b * BT2;
  const float* w1 = vt1 + (size_t)l * DD * NN;
  const float* w2 = vt2 + (size_t)l * DD * NN;
  const unsigned RB = __float_as_uint(tanh_xla(8.0f));  // plateau value bits

  const int ty = t >> 4;
  const int tx = t & 15;
  const int sk = t >> 4;
  const int sq = (t & 15) * 8;

  float acc1[8][8] = {{0.f}}, acc2[8][8] = {{0.f}};

#pragma unroll
  for (int h = 0; h < 4; ++h) {
    __syncthreads();
    {
      const size_t src = (size_t)(h * KH2 + sk) * NN;
      *(float4*)&R1h[sk][sq]     = *(const float4*)(w1 + src + r0 + sq);
      *(float4*)&R1h[sk][sq + 4] = *(const float4*)(w1 + src + r0 + sq + 4);
      *(float4*)&R2h[sk][sq]     = *(const float4*)(w2 + src + r0 + sq);
      *(float4*)&R2h[sk][sq + 4] = *(const float4*)(w2 + src + r0 + sq + 4);
      *(float4*)&C1h[sk][sq]     = *(const float4*)(w1 + src + c0 + sq);
      *(float4*)&C1h[sk][sq + 4] = *(const float4*)(w1 + src + c0 + sq + 4);
      *(float4*)&C2h[sk][sq]     = *(const float4*)(w2 + src + c0 + sq);
      *(float4*)&C2h[sk][sq + 4] = *(const float4*)(w2 + src + c0 + sq + 4);
    }
    __syncthreads();
#pragma unroll 2
    for (int kk = 0; kk < KH2; ++kk) {
      float r1[8], r2[8], c1[8], c2[8];
      *(float4*)&r1[0] = *(const float4*)&R1h[kk][8 * ty];
      *(float4*)&r1[4] = *(const float4*)&R1h[kk][8 * ty + 4];
      *(float4*)&r2[0] = *(const float4*)&R2h[kk][8 * ty];
      *(float4*)&r2[4] = *(const float4*)&R2h[kk][8 * ty + 4];
      *(float4*)&c1[0] = *(const float4*)&C1h[kk][8 * tx];
      *(float4*)&c1[4] = *(const float4*)&C1h[kk][8 * tx + 4];
      *(float4*)&c2[0] = *(const float4*)&C2h[kk][8 * tx];
      *(float4*)&c2[4] = *(const float4*)&C2h[kk][8 * tx + 4];
#pragma unroll
      for (int i = 0; i < 8; ++i)
#pragma unroll
        for (int j = 0; j < 8; ++j) {
          acc1[i][j] = fmaf(r1[i], c2[j], acc1[i][j]);  // v1_r . v2_c
          acc2[i][j] = fmaf(r2[i], c1[j], acc2[i][j]);  // v2_r . v1_c
        }
    }
  }

  // Direct tile: classify (plateau || band==RB -> bit; band>RB -> record).
#pragma unroll
  for (int i = 0; i < 8; ++i) {
    unsigned bits = 0;
#pragma unroll
    for (int j = 0; j < 8; ++j) {
      float x = 3.0f * (acc1[i][j] - acc2[i][j]);
      bool rb = (x >= KCLAMP);
      if (!rb && x > BANDLO) {
        unsigned vb = __float_as_uint(tanh_xla(x));
        if (vb == RB) rb = true;
        else if (vb > RB) {
          size_t grow = (size_t)l * NN + (r0 + 8 * ty + i);
          unsigned slot = atomicAdd(&supercnt[grow], 1u);
          if (slot < (unsigned)SRCAP)
            ((uint2*)(out + grow * NN + RECOFF))[slot] =
                make_uint2(vb, (unsigned)(c0 + 8 * tx + j));
        }
      }
      if (rb) bits |= 1u << j;
    }
    pbB[((size_t)l * NN + (r0 + 8 * ty + i)) * 768 + b * 16 + tx] = (unsigned char)bits;
  }
  // Mirror tile (b>a): mirror x = 3*(acc2-acc1) bitwise; same classification.
  if (b > a) {
#pragma unroll
    for (int j = 0; j < 8; ++j) {
      unsigned bits = 0;
#pragma unroll
      for (int i = 0; i < 8; ++i) {
        float x = 3.0f * (acc2[i][j] - acc1[i][j]);
        bool rb = (x >= KCLAMP);
        if (!rb && x > BANDLO) {
          unsigned vb = __float_as_uint(tanh_xla(x));
          if (vb == RB) rb = true;
          else if (vb > RB) {
            size_t grow = (size_t)l * NN + (c0 + 8 * tx + j);
            unsigned slot = atomicAdd(&supercnt[grow], 1u);
            if (slot < (unsigned)SRCAP)
              ((uint2*)(out + grow * NN + RECOFF))[slot] =
                  make_uint2(vb, (unsigned)(r0 + 8 * ty + i));
          }
        }
        if (rb) bits |= 1u << i;
      }
      pbB[((size_t)l * NN + (c0 + 8 * tx + j)) * 768 + a * 16 + ty] = (unsigned char)bits;
    }
  }
}

// Pass 2 (fast): one wave per row. Winners = top min(S,24) supers (value
// desc, idx asc; every super beats every RB-class entry) + first
// (24 - that) RB bits by ascending index. Records (<=512) live in the out
// row itself; read BEFORE zeroing. Fallback only if S > 512 or RB-deficient.
__global__ __launch_bounds__(256, 4) void topk_kernel(
    const ulonglong2* __restrict__ pb, const unsigned* __restrict__ supercnt,
    unsigned* __restrict__ fbcnt, unsigned* __restrict__ fblist,
    float* __restrict__ out) {
  const int t = threadIdx.x;
  const int w = t >> 6;
  const int lane = t & 63;
  const int row = blockIdx.x * 4 + w;     // layer*NN + row
  float* rp = out + (size_t)row * NN;
  const float Rclamp = tanh_xla(8.0f);
  const ull KOFF = 1ull << 62;

  ull bmx = 0ull, bmy = 0ull;
  if (lane < 48) {
    ulonglong2 bmv = pb[(size_t)row * 48 + lane];
    bmx = bmv.x; bmy = bmv.y;
  }
  const unsigned S = supercnt[row];       // wave-uniform
  bool fb = (S > (unsigned)SRCAP);
  const unsigned E = (S < 24u) ? S : 24u;
  const unsigned C24 = 24u - E;

  // Load super records (before the row gets zeroed).
  ull s_[8];
  {
    const uint2* rec = (const uint2*)(rp + RECOFF);
#pragma unroll
    for (int r = 0; r < 8; ++r) {
      unsigned slot = (unsigned)lane + 64u * r;
      ull k = 0ull;
      if (!fb && slot < S) {
        uint2 rv = rec[slot];
        k = KOFF | ((ull)rv.x << 32) | (ull)(0xFFFFu - rv.y);
      }
      s_[r] = k;
    }
  }

  // Rank RB bits: exclusive prefix of per-tile popcounts across lanes.
  unsigned cnt = (unsigned)__popcll(bmx) + (unsigned)__popcll(bmy);
  unsigned p = cnt;
#pragma unroll
  for (int d = 1; d < 64; d <<= 1) {
    unsigned o2 = __shfl_up(p, d);
    if (lane >= d) p += o2;
  }
  unsigned excl = p - cnt;
  unsigned total = __shfl(p, 63);
  if (total < C24) fb = true;             // wave-uniform

  if (fb) {
    if (lane == 0) {
      unsigned pos = atomicAdd(fbcnt, 1u);
      fblist[pos] = (unsigned)row;
    }
    return;                               // fback_kernel owns this row
  }

  // Extract top-E supers: e-th winner parked in lane e (keys unique).
  float wv = 0.0f;
  int wi = 0;
  for (unsigned e = 0; e < E; ++e) {
    ull cand = s_[0];
#pragma unroll
    for (int r = 1; r < 8; ++r) cand = (s_[r] > cand) ? s_[r] : cand;
    ull win = cand;
#pragma unroll
    for (int d = 1; d < 64; d <<= 1) {
      ull o2 = shfl_xor_u64(win, d);
      win = (o2 > win) ? o2 : win;
    }
    if (lane == (int)e) {
      wv = __uint_as_float((unsigned)((win >> 32) & 0x3FFFFFFFu));
      wi = 0xFFFF - (int)(win & 0xFFFFull);
    }
    if (cand == win) {
#pragma unroll
      for (int r = 0; r < 8; ++r) if (s_[r] == win) s_[r] = 0ull;
    }
  }

  // Zero the row (overwrites the record area too), drain, then scatter.
  float4 z = make_float4(0.f, 0.f, 0.f, 0.f);
  for (int sb = 0; sb < 24; ++sb)
    *(float4*)(rp + (size_t)(sb * 64 + lane) * 4) = z;
  asm volatile("s_waitcnt vmcnt(0)" ::: "memory");
  int need = (int)C24 - (int)excl;
  if (need > (int)cnt) need = (int)cnt;
  if (need > 0 && lane < 48) {
    int base = lane * 128;
    int done = 0;
    ull m = bmx;
    while (done < need && m) {
      int k = __builtin_ctzll(m);
      rp[base + k] = Rclamp;
      m &= m - 1; ++done;
    }
    m = bmy;
    while (done < need && m) {
      int k = __builtin_ctzll(m);
      rp[base + 64 + k] = Rclamp;
      m &= m - 1; ++done;
    }
  }
  if (lane < (int)E && wv > 0.0f) rp[wi] = wv;
}

// Fallback kernel: 1 wave per listed row (normally zero rows -> instant
// exit). Recomputes x with the identical ascending-k fmaf chains via float4
// column loads (bit-exact), then the verbatim round-9 full-list machinery.
__global__ __launch_bounds__(64) void fback_kernel(
    const float* __restrict__ vt1, const float* __restrict__ vt2,
    const unsigned* __restrict__ fbcnt, const unsigned* __restrict__ fblist,
    float* __restrict__ out) {
  const int lane = threadIdx.x;
  const unsigned RB = __float_as_uint(tanh_xla(8.0f));
  const ull KOFF = 1ull << 62;
  const ull RKEYHI = (ull)RB << 32;
  const double EMPTYD = __longlong_as_double((long long)KOFF);
  const unsigned n = fbcnt[0];

  for (unsigned it = blockIdx.x; it < n; it += gridDim.x) {
    const int row = (int)fblist[it];
    const int l = row / NN;
    const int r = row - l * NN;
    float* rp = out + (size_t)row * NN;
    const float* w1 = vt1 + (size_t)l * DD * NN;
    const float* w2 = vt2 + (size_t)l * DD * NN;

    float r1v[DD], r2v[DD];
#pragma unroll
    for (int k = 0; k < DD; ++k) {
      r1v[k] = w1[(size_t)k * NN + r];
      r2v[k] = w2[(size_t)k * NN + r];
    }

    ull mlo = 0ull, mhi = 0ull;
    double s[KK];
#pragma unroll
    for (int q = 0; q < KK; ++q) s[q] = EMPTYD;
    ull s0k = KOFF;

    for (int sb = 0; sb < 24; ++sb) {
      const unsigned gbase = (unsigned)(sb * 256 + lane * 4);
      float a1v[4] = {0.f, 0.f, 0.f, 0.f}, a2v[4] = {0.f, 0.f, 0.f, 0.f};
#pragma unroll
      for (int k = 0; k < DD; ++k) {
        float4 c1 = *(const float4*)(w1 + (size_t)k * NN + gbase);
        float4 c2 = *(const float4*)(w2 + (size_t)k * NN + gbase);
        a1v[0] = fmaf(r1v[k], c2.x, a1v[0]);
        a1v[1] = fmaf(r1v[k], c2.y, a1v[1]);
        a1v[2] = fmaf(r1v[k], c2.z, a1v[2]);
        a1v[3] = fmaf(r1v[k], c2.w, a1v[3]);
        a2v[0] = fmaf(r2v[k], c1.x, a2v[0]);
        a2v[1] = fmaf(r2v[k], c1.y, a2v[1]);
        a2v[2] = fmaf(r2v[k], c1.z, a2v[2]);
        a2v[3] = fmaf(r2v[k], c1.w, a2v[3]);
      }
      unsigned nib = 0u;
#pragma unroll
      for (int jj = 0; jj < 4; ++jj) {
        float x = 3.0f * (a1v[jj] - a2v[jj]);
        if (x >= KCLAMP) {
          nib |= 1u << jj;
        } else if (x > 0.0f) {
          float tv = tanh_xla(x);
          ull key = KOFF | ((ull)__float_as_uint(tv) << 32) |
                    (ull)(0xFFFFu - (gbase + jj));
          if (key > s0k) {
            double kd = __longlong_as_double((long long)key);
#pragma unroll
            for (int i = 0; i < KK - 1; ++i)
              s[i] = fmin(s[i + 1], fmax(s[i], kd));
            s[KK - 1] = fmax(s[KK - 1], kd);
            s0k = (ull)__double_as_longlong(s[0]);
          }
        }
      }
      if (sb < 16) mlo |= ((ull)nib) << (sb * 4);
      else         mhi |= ((ull)nib) << ((sb - 16) * 4);
    }

    float wv = 0.0f;
    int wi = 0;
    for (int rr = 0; rr < KK; ++rr) {
      ull pk = KOFF;
      if (mlo | mhi) {
        int e = mlo ? __builtin_ctzll(mlo) : (64 + __builtin_ctzll(mhi));
        int pidx = ((e >> 2) << 8) + lane * 4 + (e & 3);
        pk = KOFF | RKEYHI | (ull)(0xFFFFu - (unsigned)pidx);
      }
      ull lk = (ull)__double_as_longlong(s[KK - 1]);
      bool fromList = lk > pk;
      ull cand = fromList ? lk : pk;
      ull win = cand;
#pragma unroll
      for (int d = 1; d < 64; d <<= 1) {
        ull o2 = shfl_xor_u64(win, d);
        win = (o2 > win) ? o2 : win;
      }
      if (win == KOFF) break;
      if (lane == rr) {
        wv = __uint_as_float((unsigned)((win >> 32) & 0x3FFFFFFFu));
        wi = 0xFFFF - (int)(win & 0xFFFFull);
      }
      if (cand == win) {
        if (fromList) {
#pragma unroll
          for (int i = KK - 1; i > 0; --i) s[i] = s[i - 1];
          s[0] = EMPTYD;
        } else {
          if (mlo) mlo &= mlo - 1;
          else     mhi &= mhi - 1;
        }
      }
    }

    float4 z = make_float4(0.f, 0.f, 0.f, 0.f);
    for (int sb = 0; sb < 24; ++sb)
      *(float4*)(rp + (size_t)(sb * 64 + lane) * 4) = z;
    asm volatile("s_waitcnt vmcnt(0)" ::: "memory");
    if (wv > 0.0f) rp[wi] = wv;
  }
}

extern "C" void kernel_launch(void* const* d_in, const int* in_sizes, int n_in,
                              void* d_out, int out_size, void* d_ws, size_t ws_size,
                              hipStream_t stream) {
  const int*   idx       = (const int*)d_in[0];
  const float* scale_set = (const float*)d_in[2];
  const float* emb1      = (const float*)d_in[3];
  const float* emb2      = (const float*)d_in[4];
  const float* W1        = (const float*)d_in[5];
  const float* b1        = (const float*)d_in[6];
  const float* W2        = (const float*)d_in[7];
  const float* b2        = (const float*)d_in[8];
  float* out = (float*)d_out;

  const size_t VS = (size_t)NL * NN * DD;
  float* vt1 = (float*)d_ws;                              // 4.7 MB
  float* vt2 = vt1 + VS;                                  // 4.7 MB
  unsigned char* pbB = (unsigned char*)(vt2 + VS);        // [NL*NN][48][16B] = 14.2 MB
  unsigned* supercnt = (unsigned*)(pbB + (size_t)NL * NN * 768);   // 74 KB
  unsigned* fbcnt = supercnt + (size_t)NL * NN;                    // 4 B (+pad)
  unsigned* fblist = fbcnt + 16;                                   // 74 KB

  mlp_kernel<<<NN / MB, 256, 0, stream>>>(idx, scale_set, emb1, emb2, W1, b1, W2, b2,
                                          vt1, vt2, supercnt, fbcnt);
  xmat_kernel<<<dim3(NN / BT2, NN / BT2, NL), 256, 0, stream>>>(
      vt1, vt2, pbB, supercnt, out);
  topk_kernel<<<(NL * NN) / 4, 256, 0, stream>>>(
      (const ulonglong2*)pbB, supercnt, fbcnt, fblist, out);
  fback_kernel<<<256, 64, 0, stream>>>(vt1, vt2, fbcnt, fblist, out);
}

// Round 19
// 22823.071 us; speedup vs baseline: 1.1367x; 1.1350x over previous
//
#include <hip/hip_runtime.h>
#include <hip/hip_bf16.h>

#define NN 6144
#define DD 64
#define NL 3
#define KK 24
#define BT2 128  // pair-tile dimension (xmat kernel)
#define KH2 16   // k-quarter staged at a time
#define MB 4     // rows per block (mlp kernel)
#define SRCAP 1536   // super records per row (24 per extraction lane)
#define RECOFF 1024  // float offset of record area inside each out row
#define KCLAMP 7.99881172180175781f

typedef unsigned long long ull;

// Bit-level emulation of XLA CPU f32 tanh, FMA variant. Verified bit-exact
// vs reference (rounds 2-18, absmax 0.0).
__device__ __forceinline__ float tanh_xla(float x) {
  float xc = fminf(fmaxf(x, -KCLAMP), KCLAMP);
  float x2 = xc * xc;
  float p = -2.76076847742355e-16f;
  p = fmaf(p, x2, 2.00018790482477e-13f);
  p = fmaf(p, x2, -8.60467152213735e-11f);
  p = fmaf(p, x2, 5.12229709037114e-08f);
  p = fmaf(p, x2, 1.48572235717979e-05f);
  p = fmaf(p, x2, 6.37261928875436e-04f);
  p = fmaf(p, x2, 4.89352455891786e-03f);
  p = xc * p;
  float q = 1.19825839466702e-06f;
  q = fmaf(q, x2, 1.18534705686654e-04f);
  q = fmaf(q, x2, 2.26843463243900e-03f);
  q = fmaf(q, x2, 4.89352518554385e-03f);
  float r = p / q;
  return (fabsf(x) < 0.0004f) ? x : r;
}

// Sound lower edge of the "could reach RB" band, computed from the actual
// plateau value: r(x) <= tanh(x) + 1.5e-6, so x <= atanh(RBf - 2e-6) - 0.01
// implies r(x) < RB regardless of where r(KCLAMP) actually sits.
__device__ __forceinline__ float band_lo(float RBf) {
  float y = RBf - 2e-6f;
  return 0.5f * logf((1.0f + y) / (1.0f - y)) - 0.01f;
}

__device__ __forceinline__ ull shfl_xor_u64(ull v, int m) {
  unsigned lo = __shfl_xor((unsigned)v, m);
  unsigned hi = __shfl_xor((unsigned)(v >> 32), m);
  return ((ull)hi << 32) | lo;
}

// Kernel A: 3-layer tanh MLP chains (bit-matches Eigen). Also zeroes the
// per-row super counters and the fallback counter (graph-replay safe).
__global__ __launch_bounds__(256) void mlp_kernel(
    const int* __restrict__ idx, const float* __restrict__ scale_set,
    const float* __restrict__ emb1, const float* __restrict__ emb2,
    const float* __restrict__ W1, const float* __restrict__ b1,
    const float* __restrict__ W2, const float* __restrict__ b2,
    float* __restrict__ vt1, float* __restrict__ vt2,
    unsigned* __restrict__ supercnt, unsigned* __restrict__ fbcnt) {
  __shared__ float Wt1[DD][DD];
  __shared__ float Wt2[DD][DD];
  __shared__ float bsh1[DD], bsh2[DD];
  __shared__ __align__(16) float o1sh[MB][DD];
  __shared__ __align__(16) float o2sh[MB][DD];
  const int t = threadIdx.x;
  const int r = t >> 6;
  const int j = t & 63;
  const int grow = blockIdx.x * MB + r;

  if (t < 12) supercnt[blockIdx.x * 12 + t] = 0u;   // 1536*12 = NL*NN
  if (blockIdx.x == 0 && t == 0) fbcnt[0] = 0u;

  {
    int g = idx[grow];
    if (j < 16) {
      ((float4*)&o1sh[r][0])[j] = ((const float4*)(emb1 + (size_t)g * DD))[j];
      ((float4*)&o2sh[r][0])[j] = ((const float4*)(emb2 + (size_t)g * DD))[j];
    }
  }

  for (int l = 0; l < NL; ++l) {
    __syncthreads();
    {
      const float* w1p = W1 + ((size_t)l * DD + j) * DD + r * 16;
      const float* w2p = W2 + ((size_t)l * DD + j) * DD + r * 16;
#pragma unroll
      for (int w = 0; w < 4; ++w) {
        float4 a = *(const float4*)(w1p + 4 * w);
        float4 b = *(const float4*)(w2p + 4 * w);
        int k0 = r * 16 + 4 * w;
        Wt1[k0 + 0][j] = a.x; Wt1[k0 + 1][j] = a.y;
        Wt1[k0 + 2][j] = a.z; Wt1[k0 + 3][j] = a.w;
        Wt2[k0 + 0][j] = b.x; Wt2[k0 + 1][j] = b.y;
        Wt2[k0 + 2][j] = b.z; Wt2[k0 + 3][j] = b.w;
      }
    }
    if (t < DD) { bsh1[t] = b1[l * DD + t]; bsh2[t] = b2[l * DD + t]; }
    __syncthreads();

    const float s = scale_set[l];
    float a1 = 0.0f, a2 = 0.0f;
#pragma unroll
    for (int kb = 0; kb < 16; ++kb) {
      float4 s1 = ((const float4*)&o1sh[r][0])[kb];
      float4 s2 = ((const float4*)&o2sh[r][0])[kb];
      int k0 = 4 * kb;
      a1 = fmaf(s1.x * s, Wt1[k0 + 0][j], a1);
      a1 = fmaf(s1.y * s, Wt1[k0 + 1][j], a1);
      a1 = fmaf(s1.z * s, Wt1[k0 + 2][j], a1);
      a1 = fmaf(s1.w * s, Wt1[k0 + 3][j], a1);
      a2 = fmaf(s2.x * s, Wt2[k0 + 0][j], a2);
      a2 = fmaf(s2.y * s, Wt2[k0 + 1][j], a2);
      a2 = fmaf(s2.z * s, Wt2[k0 + 2][j], a2);
      a2 = fmaf(s2.w * s, Wt2[k0 + 3][j], a2);
    }
    float t1 = tanh_xla(3.0f * (a1 + bsh1[j]));
    float t2 = tanh_xla(3.0f * (a2 + bsh2[j]));
    __syncthreads();
    o1sh[r][j] = t1;
    o2sh[r][j] = t2;
    vt1[((size_t)l * DD + j) * NN + grow] = t1;
    vt2[((size_t)l * DD + j) * NN + grow] = t2;
  }
}

// Pass 1: antisymmetric pair-tile GEMM (validated chains; bit-exact mirror).
// Classifies every element in-register: plateau/band==RB -> bitmap bit;
// band>RB -> super record (cap 1536) into the output row's scratch area.
__global__ __launch_bounds__(256) void xmat_kernel(
    const float* __restrict__ vt1, const float* __restrict__ vt2,
    unsigned char* __restrict__ pbB,
    unsigned* __restrict__ supercnt, float* __restrict__ out) {
  __shared__ float R1h[KH2][BT2];
  __shared__ float R2h[KH2][BT2];
  __shared__ float C1h[KH2][BT2];
  __shared__ float C2h[KH2][BT2];

  const int a = blockIdx.x;
  const int b = blockIdx.y;
  if (b < a) return;
  const int l = blockIdx.z;
  const int t = threadIdx.x;
  const int r0 = a * BT2;
  const int c0 = b * BT2;
  const float* w1 = vt1 + (size_t)l * DD * NN;
  const float* w2 = vt2 + (size_t)l * DD * NN;
  const float RBf = tanh_xla(8.0f);               // exact plateau value
  const unsigned RB = __float_as_uint(RBf);
  const float BLO = band_lo(RBf);                 // sound band lower edge

  const int ty = t >> 4;
  const int tx = t & 15;
  const int sk = t >> 4;
  const int sq = (t & 15) * 8;

  float acc1[8][8] = {{0.f}}, acc2[8][8] = {{0.f}};

#pragma unroll
  for (int h = 0; h < 4; ++h) {
    __syncthreads();
    {
      const size_t src = (size_t)(h * KH2 + sk) * NN;
      *(float4*)&R1h[sk][sq]     = *(const float4*)(w1 + src + r0 + sq);
      *(float4*)&R1h[sk][sq + 4] = *(const float4*)(w1 + src + r0 + sq + 4);
      *(float4*)&R2h[sk][sq]     = *(const float4*)(w2 + src + r0 + sq);
      *(float4*)&R2h[sk][sq + 4] = *(const float4*)(w2 + src + r0 + sq + 4);
      *(float4*)&C1h[sk][sq]     = *(const float4*)(w1 + src + c0 + sq);
      *(float4*)&C1h[sk][sq + 4] = *(const float4*)(w1 + src + c0 + sq + 4);
      *(float4*)&C2h[sk][sq]     = *(const float4*)(w2 + src + c0 + sq);
      *(float4*)&C2h[sk][sq + 4] = *(const float4*)(w2 + src + c0 + sq + 4);
    }
    __syncthreads();
#pragma unroll 2
    for (int kk = 0; kk < KH2; ++kk) {
      float r1[8], r2[8], c1[8], c2[8];
      *(float4*)&r1[0] = *(const float4*)&R1h[kk][8 * ty];
      *(float4*)&r1[4] = *(const float4*)&R1h[kk][8 * ty + 4];
      *(float4*)&r2[0] = *(const float4*)&R2h[kk][8 * ty];
      *(float4*)&r2[4] = *(const float4*)&R2h[kk][8 * ty + 4];
      *(float4*)&c1[0] = *(const float4*)&C1h[kk][8 * tx];
      *(float4*)&c1[4] = *(const float4*)&C1h[kk][8 * tx + 4];
      *(float4*)&c2[0] = *(const float4*)&C2h[kk][8 * tx];
      *(float4*)&c2[4] = *(const float4*)&C2h[kk][8 * tx + 4];
#pragma unroll
      for (int i = 0; i < 8; ++i)
#pragma unroll
        for (int j = 0; j < 8; ++j) {
          acc1[i][j] = fmaf(r1[i], c2[j], acc1[i][j]);  // v1_r . v2_c
          acc2[i][j] = fmaf(r2[i], c1[j], acc2[i][j]);  // v2_r . v1_c
        }
    }
  }

  // Direct tile: classify (plateau || band==RB -> bit; band>RB -> record).
#pragma unroll
  for (int i = 0; i < 8; ++i) {
    unsigned bits = 0;
#pragma unroll
    for (int j = 0; j < 8; ++j) {
      float x = 3.0f * (acc1[i][j] - acc2[i][j]);
      bool rb = (x >= KCLAMP);
      if (!rb && x > BLO) {
        unsigned vb = __float_as_uint(tanh_xla(x));
        if (vb == RB) rb = true;
        else if (vb > RB) {
          size_t grow = (size_t)l * NN + (r0 + 8 * ty + i);
          unsigned slot = atomicAdd(&supercnt[grow], 1u);
          if (slot < (unsigned)SRCAP)
            ((uint2*)(out + grow * NN + RECOFF))[slot] =
                make_uint2(vb, (unsigned)(c0 + 8 * tx + j));
        }
      }
      if (rb) bits |= 1u << j;
    }
    pbB[((size_t)l * NN + (r0 + 8 * ty + i)) * 768 + b * 16 + tx] = (unsigned char)bits;
  }
  // Mirror tile (b>a): mirror x = 3*(acc2-acc1) bitwise; same classification.
  if (b > a) {
#pragma unroll
    for (int j = 0; j < 8; ++j) {
      unsigned bits = 0;
#pragma unroll
      for (int i = 0; i < 8; ++i) {
        float x = 3.0f * (acc2[i][j] - acc1[i][j]);
        bool rb = (x >= KCLAMP);
        if (!rb && x > BLO) {
          unsigned vb = __float_as_uint(tanh_xla(x));
          if (vb == RB) rb = true;
          else if (vb > RB) {
            size_t grow = (size_t)l * NN + (c0 + 8 * tx + j);
            unsigned slot = atomicAdd(&supercnt[grow], 1u);
            if (slot < (unsigned)SRCAP)
              ((uint2*)(out + grow * NN + RECOFF))[slot] =
                  make_uint2(vb, (unsigned)(r0 + 8 * ty + i));
          }
        }
        if (rb) bits |= 1u << i;
      }
      pbB[((size_t)l * NN + (c0 + 8 * tx + j)) * 768 + a * 16 + ty] = (unsigned char)bits;
    }
  }
}

// Pass 2 (fast): one wave per row. Winners = top min(S,24) supers (value
// desc, idx asc; every super beats every RB-class entry) + first
// (24 - that) RB bits by ascending index. Records (<=1536, 24/lane) live in
// the out row; read BEFORE zeroing. Fallback iff S > 1536 or RB-deficient.
__global__ __launch_bounds__(256, 2) void topk_kernel(
    const ulonglong2* __restrict__ pb, const unsigned* __restrict__ supercnt,
    unsigned* __restrict__ fbcnt, unsigned* __restrict__ fblist,
    float* __restrict__ out) {
  const int t = threadIdx.x;
  const int w = t >> 6;
  const int lane = t & 63;
  const int row = blockIdx.x * 4 + w;     // layer*NN + row
  float* rp = out + (size_t)row * NN;
  const float Rclamp = tanh_xla(8.0f);
  const ull KOFF = 1ull << 62;

  ull bmx = 0ull, bmy = 0ull;
  if (lane < 48) {
    ulonglong2 bmv = pb[(size_t)row * 48 + lane];
    bmx = bmv.x; bmy = bmv.y;
  }
  const unsigned S = supercnt[row];       // wave-uniform
  bool fb = (S > (unsigned)SRCAP);
  const unsigned E = (S < 24u) ? S : 24u;
  const unsigned C24 = 24u - E;

  // Load super records, 24 per lane (before the row gets zeroed).
  ull s_[24];
  {
    const uint2* rec = (const uint2*)(rp + RECOFF);
#pragma unroll
    for (int r = 0; r < 24; ++r) {
      unsigned slot = (unsigned)lane + 64u * r;
      ull k = 0ull;
      if (!fb && slot < S) {
        uint2 rv = rec[slot];
        k = KOFF | ((ull)rv.x << 32) | (ull)(0xFFFFu - rv.y);
      }
      s_[r] = k;
    }
  }

  // Rank RB bits: exclusive prefix of per-tile popcounts across lanes.
  unsigned cnt = (unsigned)__popcll(bmx) + (unsigned)__popcll(bmy);
  unsigned p = cnt;
#pragma unroll
  for (int d = 1; d < 64; d <<= 1) {
    unsigned o2 = __shfl_up(p, d);
    if (lane >= d) p += o2;
  }
  unsigned excl = p - cnt;
  unsigned total = __shfl(p, 63);
  if (total < C24) fb = true;             // wave-uniform

  if (fb) {
    if (lane == 0) {
      unsigned pos = atomicAdd(fbcnt, 1u);
      fblist[pos] = (unsigned)row;
    }
    return;                               // fback_kernel owns this row
  }

  // Extract top-E supers: e-th winner parked in lane e (keys unique).
  float wv = 0.0f;
  int wi = 0;
  for (unsigned e = 0; e < E; ++e) {
    ull cand = s_[0];
#pragma unroll
    for (int r = 1; r < 24; ++r) cand = (s_[r] > cand) ? s_[r] : cand;
    ull win = cand;
#pragma unroll
    for (int d = 1; d < 64; d <<= 1) {
      ull o2 = shfl_xor_u64(win, d);
      win = (o2 > win) ? o2 : win;
    }
    if (lane == (int)e) {
      wv = __uint_as_float((unsigned)((win >> 32) & 0x3FFFFFFFu));
      wi = 0xFFFF - (int)(win & 0xFFFFull);
    }
    if (cand == win) {
#pragma unroll
      for (int r = 0; r < 24; ++r) if (s_[r] == win) s_[r] = 0ull;
    }
  }

  // Zero the row (overwrites the record area too), drain, then scatter.
  float4 z = make_float4(0.f, 0.f, 0.f, 0.f);
  for (int sb = 0; sb < 24; ++sb)
    *(float4*)(rp + (size_t)(sb * 64 + lane) * 4) = z;
  asm volatile("s_waitcnt vmcnt(0)" ::: "memory");
  int need = (int)C24 - (int)excl;
  if (need > (int)cnt) need = (int)cnt;
  if (need > 0 && lane < 48) {
    int base = lane * 128;
    int done = 0;
    ull m = bmx;
    while (done < need && m) {
      int k = __builtin_ctzll(m);
      rp[base + k] = Rclamp;
      m &= m - 1; ++done;
    }
    m = bmy;
    while (done < need && m) {
      int k = __builtin_ctzll(m);
      rp[base + 64 + k] = Rclamp;
      m &= m - 1; ++done;
    }
  }
  if (lane < (int)E && wv > 0.0f) rp[wi] = wv;
}

// Fallback kernel: 4 waves/block, wave = one listed row (normally zero rows
// -> instant exit). Recomputes x with the identical ascending-k fmaf chains
// via float4 column loads (bit-exact), then the round-9 full-list machinery.
__global__ __launch_bounds__(256) void fback_kernel(
    const float* __restrict__ vt1, const float* __restrict__ vt2,
    const unsigned* __restrict__ fbcnt, const unsigned* __restrict__ fblist,
    float* __restrict__ out) {
  const int lane = threadIdx.x & 63;
  const int wv_ = threadIdx.x >> 6;
  const unsigned RB = __float_as_uint(tanh_xla(8.0f));
  const ull KOFF = 1ull << 62;
  const ull RKEYHI = (ull)RB << 32;
  const double EMPTYD = __longlong_as_double((long long)KOFF);
  const unsigned n = fbcnt[0];

  for (unsigned it = blockIdx.x * 4 + wv_; it < n; it += gridDim.x * 4) {
    const int row = (int)fblist[it];
    const int l = row / NN;
    const int r = row - l * NN;
    float* rp = out + (size_t)row * NN;
    const float* w1 = vt1 + (size_t)l * DD * NN;
    const float* w2 = vt2 + (size_t)l * DD * NN;

    float r1v[DD], r2v[DD];
#pragma unroll
    for (int k = 0; k < DD; ++k) {
      r1v[k] = w1[(size_t)k * NN + r];
      r2v[k] = w2[(size_t)k * NN + r];
    }

    ull mlo = 0ull, mhi = 0ull;
    double s[KK];
#pragma unroll
    for (int q = 0; q < KK; ++q) s[q] = EMPTYD;
    ull s0k = KOFF;

    for (int sb = 0; sb < 24; ++sb) {
      const unsigned gbase = (unsigned)(sb * 256 + lane * 4);
      float a1v[4] = {0.f, 0.f, 0.f, 0.f}, a2v[4] = {0.f, 0.f, 0.f, 0.f};
#pragma unroll
      for (int k = 0; k < DD; ++k) {
        float4 c1 = *(const float4*)(w1 + (size_t)k * NN + gbase);
        float4 c2 = *(const float4*)(w2 + (size_t)k * NN + gbase);
        a1v[0] = fmaf(r1v[k], c2.x, a1v[0]);
        a1v[1] = fmaf(r1v[k], c2.y, a1v[1]);
        a1v[2] = fmaf(r1v[k], c2.z, a1v[2]);
        a1v[3] = fmaf(r1v[k], c2.w, a1v[3]);
        a2v[0] = fmaf(r2v[k], c1.x, a2v[0]);
        a2v[1] = fmaf(r2v[k], c1.y, a2v[1]);
        a2v[2] = fmaf(r2v[k], c1.z, a2v[2]);
        a2v[3] = fmaf(r2v[k], c1.w, a2v[3]);
      }
      unsigned nib = 0u;
#pragma unroll
      for (int jj = 0; jj < 4; ++jj) {
        float x = 3.0f * (a1v[jj] - a2v[jj]);
        if (x >= KCLAMP) {
          nib |= 1u << jj;
        } else if (x > 0.0f) {
          float tv = tanh_xla(x);
          ull key = KOFF | ((ull)__float_as_uint(tv) << 32) |
                    (ull)(0xFFFFu - (gbase + jj));
          if (key > s0k) {
            double kd = __longlong_as_double((long long)key);
#pragma unroll
            for (int i = 0; i < KK - 1; ++i)
              s[i] = fmin(s[i + 1], fmax(s[i], kd));
            s[KK - 1] = fmax(s[KK - 1], kd);
            s0k = (ull)__double_as_longlong(s[0]);
          }
        }
      }
      if (sb < 16) mlo |= ((ull)nib) << (sb * 4);
      else         mhi |= ((ull)nib) << ((sb - 16) * 4);
    }

    float wv = 0.0f;
    int wi = 0;
    for (int rr = 0; rr < KK; ++rr) {
      ull pk = KOFF;
      if (mlo | mhi) {
        int e = mlo ? __builtin_ctzll(mlo) : (64 + __builtin_ctzll(mhi));
        int pidx = ((e >> 2) << 8) + lane * 4 + (e & 3);
        pk = KOFF | RKEYHI | (ull)(0xFFFFu - (unsigned)pidx);
      }
      ull lk = (ull)__double_as_longlong(s[KK - 1]);
      bool fromList = lk > pk;
      ull cand = fromList ? lk : pk;
      ull win = cand;
#pragma unroll
      for (int d = 1; d < 64; d <<= 1) {
        ull o2 = shfl_xor_u64(win, d);
        win = (o2 > win) ? o2 : win;
      }
      if (win == KOFF) break;
      if (lane == rr) {
        wv = __uint_as_float((unsigned)((win >> 32) & 0x3FFFFFFFu));
        wi = 0xFFFF - (int)(win & 0xFFFFull);
      }
      if (cand == win) {
        if (fromList) {
#pragma unroll
          for (int i = KK - 1; i > 0; --i) s[i] = s[i - 1];
          s[0] = EMPTYD;
        } else {
          if (mlo) mlo &= mlo - 1;
          else     mhi &= mhi - 1;
        }
      }
    }

    float4 z = make_float4(0.f, 0.f, 0.f, 0.f);
    for (int sb = 0; sb < 24; ++sb)
      *(float4*)(rp + (size_t)(sb * 64 + lane) * 4) = z;
    asm volatile("s_waitcnt vmcnt(0)" ::: "memory");
    if (wv > 0.0f) rp[wi] = wv;
  }
}

extern "C" void kernel_launch(void* const* d_in, const int* in_sizes, int n_in,
                              void* d_out, int out_size, void* d_ws, size_t ws_size,
                              hipStream_t stream) {
  const int*   idx       = (const int*)d_in[0];
  const float* scale_set = (const float*)d_in[2];
  const float* emb1      = (const float*)d_in[3];
  const float* emb2      = (const float*)d_in[4];
  const float* W1        = (const float*)d_in[5];
  const float* b1        = (const float*)d_in[6];
  const float* W2        = (const float*)d_in[7];
  const float* b2        = (const float*)d_in[8];
  float* out = (float*)d_out;

  const size_t VS = (size_t)NL * NN * DD;
  float* vt1 = (float*)d_ws;                              // 4.7 MB
  float* vt2 = vt1 + VS;                                  // 4.7 MB
  unsigned char* pbB = (unsigned char*)(vt2 + VS);        // [NL*NN][48][16B] = 14.2 MB
  unsigned* supercnt = (unsigned*)(pbB + (size_t)NL * NN * 768);   // 74 KB
  unsigned* fbcnt = supercnt + (size_t)NL * NN;                    // 4 B (+pad)
  unsigned* fblist = fbcnt + 16;                                   // 74 KB

  mlp_kernel<<<NN / MB, 256, 0, stream>>>(idx, scale_set, emb1, emb2, W1, b1, W2, b2,
                                          vt1, vt2, supercnt, fbcnt);
  xmat_kernel<<<dim3(NN / BT2, NN / BT2, NL), 256, 0, stream>>>(
      vt1, vt2, pbB, supercnt, out);
  topk_kernel<<<(NL * NN) / 4, 256, 0, stream>>>(
      (const ulonglong2*)pbB, supercnt, fbcnt, fblist, out);
  fback_kernel<<<1024, 256, 0, stream>>>(vt1, vt2, fbcnt, fblist, out);
}